// Round 5
// baseline (26.195 us; speedup 1.0000x reference)
//
#include <hip/hip_runtime.h>
#include <hip/hip_bf16.h>

#define B_SZ 4096
#define IN_D 256
#define OUT_D 256
#define NC 8

#define BM 64
#define BN 32
#define NSTEP 16            // BK=128: 16 input features per step, 16 steps

using f32x4 = __attribute__((ext_vector_type(4))) float;
using s16x8 = __attribute__((ext_vector_type(8))) short;

__device__ __forceinline__ unsigned short f2bf(float f) {
    union { float f; unsigned int u; } v; v.f = f;
    return (unsigned short)((v.u + 0x7fffu + ((v.u >> 16) & 1u)) >> 16);  // RNE
}

__device__ __forceinline__ float fast_tanh(float x) {
    float e = __expf(2.0f * x);   // saturates correctly at +-inf
    return 1.0f - 2.0f / (e + 1.0f);
}

__device__ __forceinline__ void gl2lds16(const void* g, void* l) {
    __builtin_amdgcn_global_load_lds(
        (const __attribute__((address_space(1))) unsigned int*)g,
        (__attribute__((address_space(3))) unsigned int*)l, 16, 0, 0);
}

// ---------------------------------------------------------------------------
// Fused prep. Blocks [0,512): tT[i][b] = tanh(x[b,i]) (f32, transposed).
//             Blocks [512,768): W[(i*OUT+o)*8+j] (bf16 blocked).
// ---------------------------------------------------------------------------
__global__ __launch_bounds__(256) void kan_prep(
    const float* __restrict__ x, const float* __restrict__ coefs,
    const float* __restrict__ alpha_at, const float* __restrict__ resid_scale,
    const float* __restrict__ spline_scale,
    float* __restrict__ tT, unsigned short* __restrict__ Wg)
{
    const int tid = threadIdx.x;

    if (blockIdx.x < 512) {               // ---- tanh + transpose (32b x 64i tile)
        __shared__ float tt[32][65];
        const int bid = blockIdx.x;
        const int b0 = (bid & 127) * 32;
        const int i0 = (bid >> 7) * 64;
        #pragma unroll
        for (int it = 0; it < 8; it++) {
            int e = it * 256 + tid;
            int r = e >> 6, c = e & 63;
            tt[r][c] = fast_tanh(x[(size_t)(b0 + r) * IN_D + i0 + c]);
        }
        __syncthreads();
        #pragma unroll
        for (int it = 0; it < 8; it++) {
            int e = it * 256 + tid;
            int ii = e >> 5, bb = e & 31;
            tT[(size_t)(i0 + ii) * B_SZ + b0 + bb] = tt[bb][ii];
        }
        return;
    }

    // ---- W prep (one feature i per block)
    const int i = blockIdx.x - 512;
    const int o = tid;

    float al = tanhf(alpha_at[0]);
    float mono[NC][NC];
    #pragma unroll
    for (int a = 0; a < NC; a++)
        #pragma unroll
        for (int b = 0; b < NC; b++) mono[a][b] = 0.f;
    mono[0][0] = 1.f;
    mono[1][1] = al + 1.f;
    #pragma unroll
    for (int n = 2; n < NC; n++) {
        float fn = (float)n;
        float c  = 2.f * fn + 2.f * al;
        float An = 2.f * fn * (fn + 2.f * al) * (c - 2.f);
        float Bn = (c - 1.f) * c * (c - 2.f);
        float Cn = 2.f * (fn + al - 1.f) * (fn + al - 1.f) * c;
        #pragma unroll
        for (int j = 0; j < NC; j++) {
            float tm = (j > 0 ? mono[n - 1][j - 1] : 0.f);
            mono[n][j] = (Bn * tm - Cn * mono[n - 2][j]) / An;
        }
    }

    float cf[NC];
    const float* cp = coefs + ((size_t)i * OUT_D + o) * NC;
    #pragma unroll
    for (int c = 0; c < NC; c++) cf[c] = cp[c];
    float ss = spline_scale[i * OUT_D + o];
    float rs = resid_scale[i];

    unsigned short w8[NC];
    #pragma unroll
    for (int j = 0; j < NC; j++) {
        float wv = 0.f;
        #pragma unroll
        for (int c = 0; c < NC; c++) wv += mono[c][j] * cf[c];
        wv *= ss * (1.0f / IN_D);
        if (j == 1) wv += rs * (1.0f / IN_D);
        w8[j] = f2bf(wv);
    }
    uint4 pk;
    unsigned int* pu = (unsigned int*)&pk;
    #pragma unroll
    for (int h = 0; h < 4; h++)
        pu[h] = (unsigned int)w8[2 * h] | ((unsigned int)w8[2 * h + 1] << 16);
    *(uint4*)(Wg + ((size_t)i * OUT_D + o) * NC) = pk;
}

// ---------------------------------------------------------------------------
// GEMM: out[b,o] = sum_{i,j} t[b,i]^j * W[i*8+j, o], t from tT (coalesced).
// BM=64 x BN=32, BK=128, 16 steps, 256 threads (4 waves), 512 blocks (2/CU).
// A-tile generated in-register (cvt_pk packing) -> dbuf LDS; W via gl2lds.
// ---------------------------------------------------------------------------
__global__ __launch_bounds__(256) void kan_gemm(
    const float* __restrict__ tT, const unsigned short* __restrict__ Wg,
    float* __restrict__ out)
{
    __shared__ __align__(16) unsigned short At[2][16 * BM * 8];  // 2 x 16 KB
    __shared__ __align__(16) unsigned short Wt[2][16 * BN * 8];  // 2 x 8 KB

    const int tid  = threadIdx.x;
    const int lane = tid & 63;
    const int w    = tid >> 6;
    const int lr   = lane & 15;
    const int kg   = lane >> 4;

    // XCD-aware bijective swizzle (512 % 8 == 0); 64 mblk x 8 nblk
    const int bid  = blockIdx.x;
    const int swz  = (bid & 7) * 64 + (bid >> 3);
    const int mblk = swz >> 3, nblk = swz & 7;
    const int bm = mblk * BM, bn = nblk * BN;

    f32x4 acc[2];
    acc[0] = (f32x4){0.f, 0.f, 0.f, 0.f};
    acc[1] = (f32x4){0.f, 0.f, 0.f, 0.f};

    auto stage = [&](int buf, int s) {
        // W tile: 512 x 16B chunks, 2/thread, coalesced; LDS dest linear
        const unsigned short* wb = Wg + ((size_t)(s * 16) * OUT_D + bn) * 8;
        #pragma unroll
        for (int h = 0; h < 2; h++) {
            int c  = h * 256 + tid;
            int il = c >> 5, n = c & 31;
            gl2lds16(wb + ((size_t)il * OUT_D + n) * 8, &Wt[buf][c * 8]);
        }
        // A tile: 4 power-chains/thread; t-loads lane-consecutive (coalesced)
        #pragma unroll
        for (int z = 0; z < 4; z++) {
            const int il = z * 4 + w;
            float t = tT[(size_t)(s * 16 + il) * B_SZ + bm + lane];
            float p2 = t * t, p3 = p2 * t, p4 = p3 * t;
            float p5 = p4 * t, p6 = p5 * t, p7 = p6 * t;
            __hip_bfloat162 h0 = __float22bfloat162_rn(make_float2(1.0f, t));
            __hip_bfloat162 h1 = __float22bfloat162_rn(make_float2(p2, p3));
            __hip_bfloat162 h2 = __float22bfloat162_rn(make_float2(p4, p5));
            __hip_bfloat162 h3 = __float22bfloat162_rn(make_float2(p6, p7));
            uint4 pk;
            pk.x = *(unsigned int*)&h0;
            pk.y = *(unsigned int*)&h1;
            pk.z = *(unsigned int*)&h2;
            pk.w = *(unsigned int*)&h3;
            *(uint4*)(&At[buf][(il * BM + lane) * 8]) = pk;
        }
    };

    stage(0, 0);
    __syncthreads();

    #pragma unroll
    for (int s = 0; s < NSTEP; ++s) {
        const int cur = s & 1;
        if (s + 1 < NSTEP) stage(cur ^ 1, s + 1);

        s16x8 af[4], bf[2][4];
        #pragma unroll
        for (int ks = 0; ks < 4; ks++) {
            const int il = ks * 4 + kg;
            af[ks]    = *(const s16x8*)(&At[cur][(il * BM + w * 16 + lr) * 8]);
            bf[0][ks] = *(const s16x8*)(&Wt[cur][(il * BN + lr) * 8]);
            bf[1][ks] = *(const s16x8*)(&Wt[cur][(il * BN + 16 + lr) * 8]);
        }
        #pragma unroll
        for (int ks = 0; ks < 4; ks++) {
            acc[0] = __builtin_amdgcn_mfma_f32_16x16x32_bf16(af[ks], bf[0][ks], acc[0], 0, 0, 0);
            acc[1] = __builtin_amdgcn_mfma_f32_16x16x32_bf16(af[ks], bf[1][ks], acc[1], 0, 0, 0);
        }
        __syncthreads();
    }

    // Epilogue: C/D layout col=lane&15, row=(lane>>4)*4+j; exclusive 64x32 tile
    #pragma unroll
    for (int g = 0; g < 2; g++)
        #pragma unroll
        for (int j = 0; j < 4; j++) {
            int r = bm + w * 16 + kg * 4 + j;
            int c = bn + g * 16 + lr;
            out[(size_t)r * OUT_D + c] = acc[g][j];
        }
}

extern "C" void kernel_launch(void* const* d_in, const int* in_sizes, int n_in,
                              void* d_out, int out_size, void* d_ws, size_t ws_size,
                              hipStream_t stream) {
    const float* x     = (const float*)d_in[0];
    const float* coefs = (const float*)d_in[1];
    const float* alpha = (const float*)d_in[2];
    const float* rs    = (const float*)d_in[3];
    const float* ss    = (const float*)d_in[4];
    float* out = (float*)d_out;

    unsigned short* Wg = (unsigned short*)d_ws;              // 1 MB
    float* tT = (float*)((char*)d_ws + (1 << 20));           // 4 MB

    kan_prep<<<dim3(768), dim3(256), 0, stream>>>(x, coefs, alpha, rs, ss, tT, Wg);
    kan_gemm<<<dim3((B_SZ / BM) * (OUT_D / BN)), dim3(256), 0, stream>>>(tT, Wg, out);
}

// Round 6
// 20.582 us; speedup vs baseline: 1.2727x; 1.2727x over previous
//
#include <hip/hip_runtime.h>
#include <hip/hip_bf16.h>

#define B_SZ 4096
#define IN_D 256
#define OUT_D 256
#define NC 8

#define BM 64
#define BN 32
#define SSTEPS 16           // per wave: K = 2048/4 = 512 -> 16 steps of K=32

using f32x4 = __attribute__((ext_vector_type(4))) float;
using s16x8 = __attribute__((ext_vector_type(8))) short;

__device__ __forceinline__ unsigned short f2bf(float f) {
    union { float f; unsigned int u; } v; v.f = f;
    return (unsigned short)((v.u + 0x7fffu + ((v.u >> 16) & 1u)) >> 16);  // RNE
}

__device__ __forceinline__ float fast_tanh(float x) {
    float e = __expf(2.0f * x);   // saturates correctly at +-inf
    return 1.0f - 2.0f / (e + 1.0f);
}

// ---------------------------------------------------------------------------
// Fused prep. Blocks [0,512): tT[i][b] = tanh(x[b,i]) (f32, transposed).
//             Blocks [512,768): W[(i*OUT+o)*8+j] (bf16 blocked).
// ---------------------------------------------------------------------------
__global__ __launch_bounds__(256) void kan_prep(
    const float* __restrict__ x, const float* __restrict__ coefs,
    const float* __restrict__ alpha_at, const float* __restrict__ resid_scale,
    const float* __restrict__ spline_scale,
    float* __restrict__ tT, unsigned short* __restrict__ Wg)
{
    const int tid = threadIdx.x;

    if (blockIdx.x < 512) {               // ---- tanh + transpose (32b x 64i tile)
        __shared__ float tt[32][65];
        const int bid = blockIdx.x;
        const int b0 = (bid & 127) * 32;
        const int i0 = (bid >> 7) * 64;
        #pragma unroll
        for (int it = 0; it < 8; it++) {
            int e = it * 256 + tid;
            int r = e >> 6, c = e & 63;
            tt[r][c] = fast_tanh(x[(size_t)(b0 + r) * IN_D + i0 + c]);
        }
        __syncthreads();
        #pragma unroll
        for (int it = 0; it < 8; it++) {
            int e = it * 256 + tid;
            int ii = e >> 5, bb = e & 31;
            tT[(size_t)(i0 + ii) * B_SZ + b0 + bb] = tt[bb][ii];
        }
        return;
    }

    // ---- W prep (one feature i per block)
    const int i = blockIdx.x - 512;
    const int o = tid;

    float al = tanhf(alpha_at[0]);
    float mono[NC][NC];
    #pragma unroll
    for (int a = 0; a < NC; a++)
        #pragma unroll
        for (int b = 0; b < NC; b++) mono[a][b] = 0.f;
    mono[0][0] = 1.f;
    mono[1][1] = al + 1.f;
    #pragma unroll
    for (int n = 2; n < NC; n++) {
        float fn = (float)n;
        float c  = 2.f * fn + 2.f * al;
        float An = 2.f * fn * (fn + 2.f * al) * (c - 2.f);
        float Bn = (c - 1.f) * c * (c - 2.f);
        float Cn = 2.f * (fn + al - 1.f) * (fn + al - 1.f) * c;
        #pragma unroll
        for (int j = 0; j < NC; j++) {
            float tm = (j > 0 ? mono[n - 1][j - 1] : 0.f);
            mono[n][j] = (Bn * tm - Cn * mono[n - 2][j]) / An;
        }
    }

    float cf[NC];
    const float* cp = coefs + ((size_t)i * OUT_D + o) * NC;
    #pragma unroll
    for (int c = 0; c < NC; c++) cf[c] = cp[c];
    float ss = spline_scale[i * OUT_D + o];
    float rs = resid_scale[i];

    unsigned short w8[NC];
    #pragma unroll
    for (int j = 0; j < NC; j++) {
        float wv = 0.f;
        #pragma unroll
        for (int c = 0; c < NC; c++) wv += mono[c][j] * cf[c];
        wv *= ss * (1.0f / IN_D);
        if (j == 1) wv += rs * (1.0f / IN_D);
        w8[j] = f2bf(wv);
    }
    uint4 pk;
    unsigned int* pu = (unsigned int*)&pk;
    #pragma unroll
    for (int h = 0; h < 4; h++)
        pu[h] = (unsigned int)w8[2 * h] | ((unsigned int)w8[2 * h + 1] << 16);
    *(uint4*)(Wg + ((size_t)i * OUT_D + o) * NC) = pk;
}

// ---------------------------------------------------------------------------
// Barrier-free GEMM. Block = 64x32 output tile, 4 waves = 4-way K-split
// (each wave K=512). A-fragments built IN REGISTERS (power chains: the
// mfma_16x16x32 A layout row=lane&15, k=(lane>>4)*8+j means lane's 8
// elements are exactly t^0..t^7 of one (b,i)). W-fragments loaded straight
// from L2-resident global (16B per lane). No LDS staging, no main-loop
// barriers. One LDS pass reduces the 4 K-partials. 512 blocks (2/CU).
// ---------------------------------------------------------------------------
__global__ __launch_bounds__(256) void kan_gemm(
    const float* __restrict__ tT, const unsigned short* __restrict__ Wg,
    float* __restrict__ out)
{
    __shared__ __align__(16) float lbuf[3][64 * 36];   // 27.6 KB, padded stride

    const int tid  = threadIdx.x;
    const int lane = tid & 63;
    const int kg   = tid >> 6;          // wave = K-split index 0..3
    const int lr   = lane & 15;
    const int il   = lane >> 4;         // 0..3: feature-within-step

    // XCD-aware bijective swizzle (512 % 8 == 0); 64 mblk x 8 nblk
    const int bid  = blockIdx.x;
    const int swz  = (bid & 7) * 64 + (bid >> 3);
    const int mblk = swz >> 3, nblk = swz & 7;
    const int bm = mblk * BM, bn = nblk * BN;

    f32x4 acc[4][2];
    #pragma unroll
    for (int f = 0; f < 4; f++)
        #pragma unroll
        for (int g = 0; g < 2; g++)
            acc[f][g] = (f32x4){0.f, 0.f, 0.f, 0.f};

    #pragma unroll 4
    for (int s = 0; s < SSTEPS; ++s) {
        const int i0 = kg * 64 + s * 4 + il;     // this lane's feature index

        // W fragments: 16B/lane direct from global (L2-resident)
        uint4 bw[2];
        #pragma unroll
        for (int g = 0; g < 2; g++)
            bw[g] = *(const uint4*)(Wg + ((size_t)i0 * OUT_D + bn + g * 16 + lr) * 8);

        // A fragments: power chains in registers
        s16x8 af[4];
        #pragma unroll
        for (int f = 0; f < 4; f++) {
            float t = tT[(size_t)i0 * B_SZ + bm + f * 16 + lr];
            float p2 = t * t, p3 = p2 * t, p4 = p3 * t;
            float p5 = p4 * t, p6 = p5 * t, p7 = p6 * t;
            __hip_bfloat162 h0 = __float22bfloat162_rn(make_float2(1.0f, t));
            __hip_bfloat162 h1 = __float22bfloat162_rn(make_float2(p2, p3));
            __hip_bfloat162 h2 = __float22bfloat162_rn(make_float2(p4, p5));
            __hip_bfloat162 h3 = __float22bfloat162_rn(make_float2(p6, p7));
            uint4 pk;
            pk.x = *(unsigned int*)&h0;
            pk.y = *(unsigned int*)&h1;
            pk.z = *(unsigned int*)&h2;
            pk.w = *(unsigned int*)&h3;
            af[f] = *(s16x8*)&pk;
        }

        #pragma unroll
        for (int f = 0; f < 4; f++)
            #pragma unroll
            for (int g = 0; g < 2; g++)
                acc[f][g] = __builtin_amdgcn_mfma_f32_16x16x32_bf16(
                    af[f], *(s16x8*)&bw[g], acc[f][g], 0, 0, 0);
    }

    // ---- K-split reduction: waves 1..3 dump, wave 0 accumulates + stores
    if (kg > 0) {
        float* dst = &lbuf[kg - 1][lane * 36];
        #pragma unroll
        for (int f = 0; f < 4; f++)
            #pragma unroll
            for (int g = 0; g < 2; g++)
                *(f32x4*)(dst + f * 8 + g * 4) = acc[f][g];
    }
    __syncthreads();
    if (kg == 0) {
        #pragma unroll
        for (int r = 0; r < 3; r++) {
            const float* src = &lbuf[r][lane * 36];
            #pragma unroll
            for (int f = 0; f < 4; f++)
                #pragma unroll
                for (int g = 0; g < 2; g++)
                    acc[f][g] += *(const f32x4*)(src + f * 8 + g * 4);
        }
        // C/D layout: col = lane&15, row = (lane>>4)*4 + j
        #pragma unroll
        for (int f = 0; f < 4; f++)
            #pragma unroll
            for (int g = 0; g < 2; g++)
                #pragma unroll
                for (int j = 0; j < 4; j++) {
                    int r = bm + f * 16 + il * 4 + j;
                    int c = bn + g * 16 + lr;
                    out[(size_t)r * OUT_D + c] = acc[f][g][j];
                }
    }
}

extern "C" void kernel_launch(void* const* d_in, const int* in_sizes, int n_in,
                              void* d_out, int out_size, void* d_ws, size_t ws_size,
                              hipStream_t stream) {
    const float* x     = (const float*)d_in[0];
    const float* coefs = (const float*)d_in[1];
    const float* alpha = (const float*)d_in[2];
    const float* rs    = (const float*)d_in[3];
    const float* ss    = (const float*)d_in[4];
    float* out = (float*)d_out;

    unsigned short* Wg = (unsigned short*)d_ws;              // 1 MB
    float* tT = (float*)((char*)d_ws + (1 << 20));           // 4 MB

    kan_prep<<<dim3(768), dim3(256), 0, stream>>>(x, coefs, alpha, rs, ss, tT, Wg);
    kan_gemm<<<dim3((B_SZ / BM) * (OUT_D / BN)), dim3(256), 0, stream>>>(tT, Wg, out);
}